// Round 5
// baseline (49176.135 us; speedup 1.0000x reference)
//
#include <hip/hip_runtime.h>
#include <cmath>

#define BB 64      // batch
#define TT 512     // seq len
#define HH 512     // hidden
#define GG 2048    // 4*H
#define TCH 64     // time chunk
#define LDT 132    // xg_gemm LDS tile row stride (floats)

// ---------------------------------------------------------------------------
// xg GEMM (unchanged — verified correct)
// ---------------------------------------------------------------------------
template<bool GATHER>
__global__ __launch_bounds__(256) void xg_gemm(
    const float* __restrict__ Xsrc, const int* __restrict__ tok,
    const float* __restrict__ Wih, const float* __restrict__ bih,
    const float* __restrict__ bhh, float* __restrict__ XG, int t0)
{
  __shared__ float As[32 * LDT];
  __shared__ float Bs[32 * LDT];
  const int tid = threadIdx.x;
  const int tc = tid & 15, tr = tid >> 4;
  const int m0 = blockIdx.x * 128;
  const int g0 = blockIdx.y * 128;

  float acc[8][8];
#pragma unroll
  for (int i = 0; i < 8; ++i)
#pragma unroll
    for (int j = 0; j < 8; ++j) acc[i][j] = 0.f;

  float4 ra[4], rb[4];
#pragma unroll
  for (int i = 0; i < 4; ++i) {
    const int f = tid + i * 256;
    ra[i] = *(const float4*)&Wih[(size_t)(g0 + (f >> 3)) * HH + ((f & 7) << 2)];
  }
#pragma unroll
  for (int i = 0; i < 4; ++i) {
    const int f = tid + i * 256;
    if (GATHER) {
      const int m = m0 + (f >> 3);
      const int tok_i = tok[(m & 63) * TT + t0 + (m >> 6)];
      rb[i] = *(const float4*)&Xsrc[(size_t)tok_i * HH + ((f & 7) << 2)];
    } else {
      rb[i] = *(const float4*)&Xsrc[((size_t)(t0 + (m0 >> 6) + (f >> 9)) * HH
                                     + ((f >> 4) & 31)) * BB + ((f & 15) << 2)];
    }
  }

  for (int kt = 0; kt < 16; ++kt) {
#pragma unroll
    for (int i = 0; i < 4; ++i) {
      const int f = tid + i * 256;
      const int row = f >> 3, c4 = f & 7, s = c4 & 3;
      const int col = (((row >> 2) ^ s) << 2) + (row & 3);
      As[(c4 * 4 + 0) * LDT + col] = ra[i].x;
      As[(c4 * 4 + 1) * LDT + col] = ra[i].y;
      As[(c4 * 4 + 2) * LDT + col] = ra[i].z;
      As[(c4 * 4 + 3) * LDT + col] = ra[i].w;
    }
#pragma unroll
    for (int i = 0; i < 4; ++i) {
      const int f = tid + i * 256;
      if (GATHER) {
        const int row = f >> 3, c4 = f & 7, s = c4 & 3;
        const int col = (((row >> 2) ^ s) << 2) + (row & 3);
        Bs[(c4 * 4 + 0) * LDT + col] = rb[i].x;
        Bs[(c4 * 4 + 1) * LDT + col] = rb[i].y;
        Bs[(c4 * 4 + 2) * LDT + col] = rb[i].z;
        Bs[(c4 * 4 + 3) * LDT + col] = rb[i].w;
      } else {
        const int kk = (f >> 4) & 31, s = (kk >> 2) & 3;
        const int mq = (((f >> 9) << 4) + (f & 15)) ^ s;
        *(float4*)&Bs[kk * LDT + (mq << 2)] = rb[i];
      }
    }
    __syncthreads();
    if (kt < 15) {
      const int k0 = (kt + 1) * 32;
#pragma unroll
      for (int i = 0; i < 4; ++i) {
        const int f = tid + i * 256;
        ra[i] = *(const float4*)&Wih[(size_t)(g0 + (f >> 3)) * HH + k0 + ((f & 7) << 2)];
      }
#pragma unroll
      for (int i = 0; i < 4; ++i) {
        const int f = tid + i * 256;
        if (GATHER) {
          const int m = m0 + (f >> 3);
          const int tok_i = tok[(m & 63) * TT + t0 + (m >> 6)];
          rb[i] = *(const float4*)&Xsrc[(size_t)tok_i * HH + k0 + ((f & 7) << 2)];
        } else {
          rb[i] = *(const float4*)&Xsrc[((size_t)(t0 + (m0 >> 6) + (f >> 9)) * HH
                                         + k0 + ((f >> 4) & 31)) * BB + ((f & 15) << 2)];
        }
      }
    }
#pragma unroll
    for (int k = 0; k < 32; ++k) {
      const int s = (k >> 2) & 3;
      const float4 a0 = *(const float4*)&As[k * LDT + ((tr ^ s) << 2)];
      const float4 a1 = *(const float4*)&As[k * LDT + ((16 + (tr ^ s)) << 2)];
      const float4 b0 = *(const float4*)&Bs[k * LDT + ((tc ^ s) << 2)];
      const float4 b1 = *(const float4*)&Bs[k * LDT + ((16 + (tc ^ s)) << 2)];
      const float av[8] = {a0.x, a0.y, a0.z, a0.w, a1.x, a1.y, a1.z, a1.w};
      const float bv[8] = {b0.x, b0.y, b0.z, b0.w, b1.x, b1.y, b1.z, b1.w};
#pragma unroll
      for (int i2 = 0; i2 < 8; ++i2)
#pragma unroll
        for (int j2 = 0; j2 < 8; ++j2)
          acc[i2][j2] = fmaf(av[i2], bv[j2], acc[i2][j2]);
    }
    __syncthreads();
  }

#pragma unroll
  for (int ah = 0; ah < 2; ++ah)
#pragma unroll
    for (int i = 0; i < 4; ++i) {
      const int gc = g0 + ah * 64 + tr * 4 + i;
      const float bias = bih[gc] + bhh[gc];
#pragma unroll
      for (int bh = 0; bh < 2; ++bh) {
        const int tl_ = (m0 >> 6) + bh;
        float4 v;
        v.x = acc[ah * 4 + i][bh * 4 + 0] + bias;
        v.y = acc[ah * 4 + i][bh * 4 + 1] + bias;
        v.z = acc[ah * 4 + i][bh * 4 + 2] + bias;
        v.w = acc[ah * 4 + i][bh * 4 + 3] + bias;
        *(float4*)&XG[((size_t)tl_ * GG + gc) * BB + (tc << 2)] = v;
      }
    }
}

// ---------------------------------------------------------------------------
// Persistent recurrence, v3.
//  - thread = (rp 0..15 rows-of-4, ks 0..15 k-segs of 32): W = 4 rows x 32 k
//    in 128 VGPRs; LDS reads halved vs v2 (64 ds_read_b128/thread/step).
//  - h staged with vectorized coherent loads (global_load_dwordx4 sc0 sc1),
//    bank-rotated LDS layout (b*144 + ks*9 + cc).
//  - flag-based group barrier: one store per WG to its own word, wave-0
//    vector poll of all 32 flags (no atomic-add contention).
//  - XG prefetched before staging (latency overlapped).
// ---------------------------------------------------------------------------
__global__ __launch_bounds__(256, 1) void lstm_chunk(
    const float* __restrict__ XG, const float* __restrict__ Whh,
    float* __restrict__ h0, float* __restrict__ h1,
    float* __restrict__ c, float* __restrict__ Y,
    unsigned* __restrict__ flag, int t0, int l)
{
  const int tid = threadIdx.x;
  const int grp = blockIdx.x & 7;
  const int mid = blockIdx.x >> 3;
  const int rp = tid >> 4;          // 0..15: row within 16
  const int ks = tid & 15;          // 0..15: 32-wide k segment

  __shared__ float4 hs4[8 * 144];
  __shared__ float gs[512];

  // W_hh rows -> registers: thread owns gate rows {q*512 + mid*16 + rp, q=0..3}
  float4 w[4][8];
#pragma unroll
  for (int j = 0; j < 4; ++j)
#pragma unroll
    for (int cc = 0; cc < 8; ++cc)
      w[j][cc] = *(const float4*)&Whh[(size_t)((j << 9) + mid * 16 + rp) * HH
                                      + ks * 32 + cc * 4];

  // c for this chunk in registers (tid<128: one (hc,b) cell each)
  const int hc_l = tid >> 3;
  const int bb_l = tid & 7;
  const int hc_own = mid * 16 + hc_l;
  const int Bg_own = 8 * grp + bb_l;
  float creg = 0.f;
  if (t0 > 0 && tid < 128) creg = c[(size_t)hc_own * BB + Bg_own];

  for (int tl = 0; tl < TCH; ++tl) {
    const int t = t0 + tl;
    const int first = (t == 0) ? 1 : 0;
    const float* h_in = (t & 1) ? h1 : h0;
    float* h_out = (t & 1) ? h0 : h1;

    // XG prefetch (tid<128) — independent of h, overlaps staging latency
    float xgv[4];
    if (tid < 128) {
#pragma unroll
      for (int q = 0; q < 4; ++q)
        xgv[q] = XG[((size_t)tl * GG + (q << 9) + hc_own) * BB + Bg_own];
    }

    float p[4][8];
#pragma unroll
    for (int j = 0; j < 4; ++j)
#pragma unroll
      for (int b = 0; b < 8; ++b) p[j][b] = 0.f;

    if (!first) {
      // ---- stage h slice [8][512] via coherent vector loads ----
      float4 hv4[4];
#pragma unroll
      for (int i = 0; i < 4; ++i) {
        const int f = tid + i * 256;
        const int b = f >> 7, c4 = f & 127;
        const float* src = &h_in[(size_t)(8 * grp + b) * HH + (c4 << 2)];
        asm volatile("global_load_dwordx4 %0, %1, off sc0 sc1"
                     : "=v"(hv4[i]) : "v"(src));
      }
      asm volatile("s_waitcnt vmcnt(0)" ::: "memory");
      __builtin_amdgcn_sched_barrier(0);
#pragma unroll
      for (int i = 0; i < 4; ++i) {
        const int f = tid + i * 256;
        const int b = f >> 7, c4 = f & 127;
        hs4[b * 144 + (c4 >> 3) * 9 + (c4 & 7)] = hv4[i];
      }
      __syncthreads();

      // ---- compute: 4 rows x 32 k vs 8 batches ----
#pragma unroll
      for (int cc = 0; cc < 8; ++cc) {
#pragma unroll
        for (int b = 0; b < 8; ++b) {
          const float4 hv = hs4[b * 144 + ks * 9 + cc];
#pragma unroll
          for (int j = 0; j < 4; ++j) {
            p[j][b] += hv.x * w[j][cc].x + hv.y * w[j][cc].y
                     + hv.z * w[j][cc].z + hv.w * w[j][cc].w;
          }
        }
      }
      // reduce across the 16 ks lanes (bits 0..3 of tid)
#pragma unroll
      for (int j = 0; j < 4; ++j)
#pragma unroll
        for (int b = 0; b < 8; ++b) {
          float v = p[j][b];
          v += __shfl_xor(v, 1);
          v += __shfl_xor(v, 2);
          v += __shfl_xor(v, 4);
          v += __shfl_xor(v, 8);
          p[j][b] = v;
        }
      if (ks == 0) {
#pragma unroll
        for (int j = 0; j < 4; ++j)
#pragma unroll
          for (int b = 0; b < 8; ++b)
            gs[((j << 4) + rp) * 8 + b] = p[j][b];
      }
    }
    __syncthreads();   // gs ready (or skipped when first)

    // ---- gating ----
    if (tid < 128) {
      float gv[4];
#pragma unroll
      for (int q = 0; q < 4; ++q) {
        float x = xgv[q];
        if (!first) x += gs[(q * 16 + hc_l) * 8 + bb_l];
        gv[q] = x;
      }
      const float cold = first ? 0.f : creg;
      const float si = 1.f / (1.f + expf(-gv[0]));
      const float sf = 1.f / (1.f + expf(-gv[1]));
      const float so = 1.f / (1.f + expf(-gv[3]));
      const float cn = sf * cold + si * tanhf(gv[2]);
      const float hn = so * tanhf(cn);
      creg = cn;
      __hip_atomic_store(&h_out[(size_t)Bg_own * HH + hc_own], hn,
                         __ATOMIC_RELAXED, __HIP_MEMORY_SCOPE_AGENT);
      Y[((size_t)t * HH + hc_own) * BB + Bg_own] = hn;
    }

    // ---- flag barrier: own-word store + wave-0 vector poll ----
    asm volatile("s_waitcnt vmcnt(0)" ::: "memory");
    __syncthreads();
    const unsigned sid = (unsigned)(l * TT + t + 1);
    if (tid == 0)
      __hip_atomic_store(&flag[grp * 32 + mid], sid,
                         __ATOMIC_RELAXED, __HIP_MEMORY_SCOPE_AGENT);
    if (tid < 64) {
      const int fi = grp * 32 + (tid & 31);
      while (__hip_atomic_load(&flag[fi], __ATOMIC_RELAXED,
                               __HIP_MEMORY_SCOPE_AGENT) < sid)
        __builtin_amdgcn_s_sleep(1);
    }
    __syncthreads();
  }

  if (tid < 128) c[(size_t)hc_own * BB + Bg_own] = creg;
}

// ---------------------------------------------------------------------------
__global__ __launch_bounds__(64) void cls_kernel(
    const float* __restrict__ Y, const float* __restrict__ Wcls,
    const float* __restrict__ bcls, float* __restrict__ out)
{
  __shared__ float feat[512];
  const int b = blockIdx.x, tid = threadIdx.x;
  for (int k = tid; k < HH; k += 64)
    feat[k] = Y[((size_t)(TT - 1) * HH + k) * BB + b];
  __syncthreads();
  if (tid < 20) {
    float acc = bcls[tid];
    for (int k = 0; k < HH; ++k) acc = fmaf(feat[k], Wcls[tid * HH + k], acc);
    out[b * 20 + tid] = acc;
  }
}

// ---------------------------------------------------------------------------
extern "C" void kernel_launch(void* const* d_in, const int* in_sizes, int n_in,
                              void* d_out, int out_size, void* d_ws, size_t ws_size,
                              hipStream_t stream) {
  (void)in_sizes; (void)n_in; (void)out_size; (void)ws_size;
  const int*   tok  = (const int*)d_in[0];
  const float* emb  = (const float*)d_in[1];
  const float* Wih  = (const float*)d_in[2];
  const float* Whh  = (const float*)d_in[3];
  const float* bih  = (const float*)d_in[4];
  const float* bhh  = (const float*)d_in[5];
  const float* Wcls = (const float*)d_in[6];
  const float* bcls = (const float*)d_in[7];
  float* out = (float*)d_out;

  // ws: Y [T][H][B] | XG [TCH][4H][B] | h0 [B][H] | h1 [B][H] | c [H][B] | flags
  float* Y  = (float*)d_ws;
  float* XG = Y + (size_t)TT * HH * BB;
  float* h0 = XG + (size_t)TCH * GG * BB;
  float* h1 = h0 + (size_t)BB * HH;
  float* c  = h1 + (size_t)BB * HH;
  unsigned* flag = (unsigned*)(c + (size_t)HH * BB);

  hipMemsetAsync(flag, 0, 8 * 32 * sizeof(unsigned), stream);

  for (int l = 0; l < 5; ++l) {
    const float* wih_l = Wih + (size_t)l * GG * HH;
    const float* whh_l = Whh + (size_t)l * GG * HH;
    const float* bih_l = bih + (size_t)l * GG;
    const float* bhh_l = bhh + (size_t)l * GG;
    for (int t0 = 0; t0 < TT; t0 += TCH) {
      if (l == 0)
        xg_gemm<true><<<dim3(32, 16), 256, 0, stream>>>(emb, tok, wih_l, bih_l, bhh_l, XG, t0);
      else
        xg_gemm<false><<<dim3(32, 16), 256, 0, stream>>>(Y, nullptr, wih_l, bih_l, bhh_l, XG, t0);
      lstm_chunk<<<256, 256, 0, stream>>>(XG, whh_l, h0, h1, c, Y, flag, t0, l);
    }
  }
  cls_kernel<<<64, 64, 0, stream>>>(Y, Wcls, bcls, out);
}